// Round 6
// baseline (81.267 us; speedup 1.0000x reference)
//
#include <hip/hip_runtime.h>
#include <math.h>

#define NPTS 8192
#define NB 4
#define SCALE (1.0f/32.0f)
#define JSPLIT 4
#define JCH (NPTS/JSPLIT)        // 2048 b-points staged per block (32 KB LDS)
#define NTILE (JCH/16)           // 128 j-tiles of 16 b-points
#define ISPLIT 32
#define APB 256                  // a-points per block: 4 waves x 64
#define BPD (ISPLIT*JSPLIT)      // 128 blocks per (batch,dir)
#define NBLK (NB*2*BPD)          // 1024
#define BIG 3.0e38f

typedef _Float16 half4 __attribute__((ext_vector_type(4)));
typedef float f32x4 __attribute__((ext_vector_type(4)));
typedef unsigned long long u64;
typedef unsigned int u32;
union H4 { half4 h; u64 u; };

// ws layout:
//   [0, 256K)      minbits u32[NB][2][NPTS]  (prep inits to 0x7F7F7F7F)
//   [256K, +32)    tk u32[8]  (tickets per (batch,dir), prep zeroes)
//   [256K+32, +4)  tk2 u32    (global ticket, prep zeroes)
//   [256K+64, +32) hm float[8] (no init needed)
//   [1M, 2M)       AV u64[src2][khalf2][NB][NPTS]
//   [2M, 3M)       BV u64[src2][khalf2][NB][NPTS]

__device__ __forceinline__ u32 agent_load_u32(const u32* p) {
    return __hip_atomic_load(p, __ATOMIC_RELAXED, __HIP_MEMORY_SCOPE_AGENT);
}
__device__ __forceinline__ float agent_load_f32(const float* p) {
    return __hip_atomic_load(p, __ATOMIC_RELAXED, __HIP_MEMORY_SCOPE_AGENT);
}

// Two-term f16 split, 8 Gram terms:
//   b-side [uxh,uxl,uxh,uyh | uyl,uyh,wh,wl]  (u=-2b', w=|b'|^2)
//   a-side [axh,axh,axl,ayh | ayh,ayl, 1, 1]
//   dot = -2<a',b'> + |b'|^2 = d2' - a2'
__global__ __launch_bounds__(256) void haus_prep(
    const float* __restrict__ pred, const float* __restrict__ targ,
    u64* __restrict__ AV, u64* __restrict__ BV,
    u32* __restrict__ minbits, u32* __restrict__ tks)
{
    int tid = blockIdx.x * 256 + threadIdx.x;       // 0..65535
    minbits[tid] = 0x7F7F7F7Fu;                     // +3.39e38 for atomicMin
    if (tid < 16) tks[tid] = 0u;                    // tk[8] + tk2 (+pad)
    int src = tid >> 15;                            // 0=pred, 1=targ
    int idx = tid & 32767;                          // batch*NPTS + pt
    const float2* in = (const float2*)(src ? targ : pred);
    float2 p = in[idx];
    float xs = p.x * SCALE, ys = p.y * SCALE;
    _Float16 axh = (_Float16)xs; _Float16 axl = (_Float16)(xs - (float)axh);
    _Float16 ayh = (_Float16)ys; _Float16 ayl = (_Float16)(ys - (float)ayh);
    H4 alo, ahi;
    alo.h = (half4){axh, axh, axl, ayh};
    ahi.h = (half4){ayh, ayl, (_Float16)1.0f, (_Float16)1.0f};
    float ux = -2.0f * xs, uy = -2.0f * ys;
    _Float16 uxh = (_Float16)ux; _Float16 uxl = (_Float16)(ux - (float)uxh);
    _Float16 uyh = (_Float16)uy; _Float16 uyl = (_Float16)(uy - (float)uyh);
    float w = fmaf(xs, xs, ys * ys);
    _Float16 wh = (_Float16)w; _Float16 wl = (_Float16)(w - (float)wh);
    H4 blo, bhi;
    blo.h = (half4){uxh, uxl, uxh, uyh};
    bhi.h = (half4){uyl, uyh, wh, wl};
    AV[(src*2+0)*(NB*NPTS) + idx] = alo.u;
    AV[(src*2+1)*(NB*NPTS) + idx] = ahi.u;
    BV[(src*2+0)*(NB*NPTS) + idx] = blo.u;
    BV[(src*2+1)*(NB*NPTS) + idx] = bhi.u;
}

// fold 4 acc values into mn: 2 x v_min3_f32 after fusion
#define FOLD(acc, mn) { float _t = fminf(fminf(acc[0], acc[1]), acc[2]); \
                        mn = fminf(fminf(acc[3], _t), mn); }
#define MFMA4(dst, L) \
    dst##0 = __builtin_amdgcn_mfma_f32_16x16x16f16(L.h, R0.h, z, 0, 0, 0); \
    dst##1 = __builtin_amdgcn_mfma_f32_16x16x16f16(L.h, R1.h, z, 0, 0, 0); \
    dst##2 = __builtin_amdgcn_mfma_f32_16x16x16f16(L.h, R2.h, z, 0, 0, 0); \
    dst##3 = __builtin_amdgcn_mfma_f32_16x16x16f16(L.h, R3.h, z, 0, 0, 0);
#define FOLD4(src) FOLD(src##0, mn0) FOLD(src##1, mn1) \
                   FOLD(src##2, mn2) FOLD(src##3, mn3)

// 16x16x16 f16 MFMA, D[row=b-point][col=a-point], K=8 useful (k 8..15 zeroed
// on the B operand). A-frag: lane l holds A[row=l&15][k=4*(l>>4)+j]; B-frag:
// B[k=4*(l>>4)+j][col=l&15]; C/D: col=l&15, row=4*(l>>4)+reg.
__global__ __launch_bounds__(256, 4) void haus_main(
    const float* __restrict__ pred, const float* __restrict__ targ,
    const u64* __restrict__ AV, const u64* __restrict__ BV,
    u32* __restrict__ minbits, float* __restrict__ hm,
    u32* __restrict__ tk, u32* __restrict__ tk2, float* __restrict__ out)
{
    __shared__ u64 sL[2 * JCH];                      // [khalf][point], 32 KB
    __shared__ float sred[4];
    __shared__ u32 sflag;

    int bid = blockIdx.x;                            // 1024
    int jh   = bid & (JSPLIT-1); bid >>= 2;
    int iblk = bid & (ISPLIT-1); bid >>= 5;
    int dir  = bid & 1;          bid >>= 1;
    int batch = bid;
    int bd = batch * 2 + dir;

    int tid = threadIdx.x;
    int wave = tid >> 6, lane = tid & 63;
    int r = lane & 15, kq = lane >> 4;
    int asrc = dir, bsrc = dir ^ 1;

    // Stage this block's j-chunk of pre-transformed b-side halves (linear)
    const u64* s0 = BV + (size_t)(bsrc*2+0)*(NB*NPTS) + batch*NPTS + jh*JCH;
    const u64* s1 = BV + (size_t)(bsrc*2+1)*(NB*NPTS) + batch*NPTS + jh*JCH;
    #pragma unroll
    for (int it = 0; it < JCH/256; ++it) {
        sL[it*256 + tid]       = s0[it*256 + tid];
        sL[JCH + it*256 + tid] = s1[it*256 + tid];
    }

    // B-operand frags: 4 chains x 16 a-points; k-groups 2,3 are zero.
    int ibase = iblk*APB + wave*64;
    H4 R0, R1, R2, R3;
    if (kq < 2) {
        const u64* avk = AV + (size_t)(asrc*2+kq)*(NB*NPTS) + batch*NPTS + ibase + r;
        R0.u = avk[0]; R1.u = avk[16]; R2.u = avk[32]; R3.u = avk[48];
    } else {
        R0.u = 0; R1.u = 0; R2.u = 0; R3.u = 0;
    }

    __syncthreads();

    // A-operand read: k-groups 2,3 duplicate groups 0,1 (B is zero there).
    const u64* lp = sL + (size_t)(kq & 1)*JCH + r;
    const f32x4 z = {};
    float mn0 = BIG, mn1 = BIG, mn2 = BIG, mn3 = BIG;

    H4 La, Lb;
    La.u = lp[0];
    f32x4 aA0, aA1, aA2, aA3, aB0, aB1, aB2, aB3;
    MFMA4(aA, La)
    Lb.u = lp[16];
    for (int t = 1; t < NTILE - 1; t += 2) {
        MFMA4(aB, Lb)                 // tile t
        La.u = lp[(t + 1) * 16];
        FOLD4(aA)                     // fold tile t-1 while B flies
        MFMA4(aA, La)                 // tile t+1
        Lb.u = lp[(t + 2) * 16];
        FOLD4(aB)
    }
    MFMA4(aB, Lb)                     // tile 127
    FOLD4(aA)
    FOLD4(aB)

    // reduce across the 4 k-groups (rows 0..15 of each col)
    mn0 = fminf(mn0, __shfl_xor(mn0, 16)); mn0 = fminf(mn0, __shfl_xor(mn0, 32));
    mn1 = fminf(mn1, __shfl_xor(mn1, 16)); mn1 = fminf(mn1, __shfl_xor(mn1, 32));
    mn2 = fminf(mn2, __shfl_xor(mn2, 16)); mn2 = fminf(mn2, __shfl_xor(mn2, 32));
    mn3 = fminf(mn3, __shfl_xor(mn3, 16)); mn3 = fminf(mn3, __shfl_xor(mn3, 32));

    // lane (kq, r) commits chain kq's a-point: i = ibase + 16*kq + r
    {
        float mv = (kq == 0) ? mn0 : (kq == 1) ? mn1 : (kq == 2) ? mn2 : mn3;
        int i = ibase + kq*16 + r;
        const float2* ain = (const float2*)(asrc ? targ : pred) + (size_t)batch*NPTS;
        float2 p = ain[i];
        float xs = p.x*SCALE, ys = p.y*SCALE;
        float v = fmaxf(mv + fmaf(xs, xs, ys*ys), 0.0f);
        atomicMin(minbits + ((size_t)bd << 13) + i, __float_as_uint(v));
    }

    // ---- per-(batch,dir): last of 128 blocks reduces its row ----
    __threadfence();
    if (tid == 0) sflag = atomicAdd(&tk[bd], 1u);
    __syncthreads();
    if (sflag == BPD - 1) {
        const u32* row = minbits + ((size_t)bd << 13);
        float m = 0.0f;
        #pragma unroll
        for (int k = 0; k < NPTS/256; ++k)
            m = fmaxf(m, __uint_as_float(agent_load_u32(row + k*256 + tid)));
        #pragma unroll
        for (int o = 32; o; o >>= 1) m = fmaxf(m, __shfl_xor(m, o));
        if (lane == 0) sred[wave] = m;
        __syncthreads();
        if (tid == 0) {
            hm[bd] = fmaxf(fmaxf(sred[0], sred[1]), fmaxf(sred[2], sred[3]));
            __threadfence();
            u32 o2 = atomicAdd(tk2, 1u);
            if (o2 == NB*2 - 1) {                   // 8th reducer finalizes
                __threadfence();
                float s = 0.0f;
                #pragma unroll
                for (int b = 0; b < NB; ++b) {
                    float h0 = agent_load_f32(&hm[2*b]);
                    float h1 = agent_load_f32(&hm[2*b + 1]);
                    s += sqrtf(fmaxf(h0, h1));
                }
                out[0] = s * (32.0f / NB);          // unscale + mean
            }
        }
    }
}

extern "C" void kernel_launch(void* const* d_in, const int* in_sizes, int n_in,
                              void* d_out, int out_size, void* d_ws, size_t ws_size,
                              hipStream_t stream) {
    const float* pred = (const float*)d_in[0];   // [4,8192,2] f32
    const float* targ = (const float*)d_in[1];   // [4,8192,2] f32

    u32*   minbits = (u32*)d_ws;
    u32*   tks     = (u32*)((char*)d_ws + 262144);       // tk[8], tk2, pad
    u32*   tk      = tks;
    u32*   tk2     = tks + 8;
    float* hm      = (float*)((char*)d_ws + 262144 + 64);
    u64*   AV      = (u64*)((char*)d_ws + (1u << 20));
    u64*   BV      = (u64*)((char*)d_ws + (2u << 20));

    hipLaunchKernelGGL(haus_prep, dim3(256), dim3(256), 0, stream,
                       pred, targ, AV, BV, minbits, tks);
    hipLaunchKernelGGL(haus_main, dim3(NBLK), dim3(256), 0, stream,
                       pred, targ, AV, BV, minbits, hm, tk, tk2, (float*)d_out);
}

// Round 7
// 41.892 us; speedup vs baseline: 1.9399x; 1.9399x over previous
//
#include <hip/hip_runtime.h>
#include <math.h>

#define NPTS 8192
#define NB 4
#define GW 64                  // grid is GW x GW cells
#define NCELL (GW*GW)
#define CS 8.0f                // cell size (512 / GW)
#define INV_CS 0.125f
#define CAP 16                 // points stored per cell (mean occupancy = 2)
#define NOVF NPTS              // overflow list capacity (full safety)

typedef unsigned int u32;

// ws layout:
//   [0, 128K)        cnt  u32[8][NCELL]        (zeroed by memset)
//   [128K, +32)      ovfn u32[8]               (zeroed)
//   [128K+32, +32)   hm   u32[8]  max d2 bits  (zeroed; values >= 0)
//   [1M, 1M+4M)      pts  float2[8][NCELL][CAP]
//   [6M, 6M+512K)    ovf  float2[8][NOVF]
// grid index g = batch*2 + src  (src: 0=pred, 1=targ)

__global__ __launch_bounds__(256) void hgrid_build(
    const float2* __restrict__ pred, const float2* __restrict__ targ,
    u32* __restrict__ cnt, float2* __restrict__ pts,
    u32* __restrict__ ovfn, float2* __restrict__ ovf)
{
    int tid = blockIdx.x * 256 + threadIdx.x;      // 0..65535
    int src = tid >> 15, rem = tid & 32767;
    int batch = rem >> 13, idx = rem & 8191;
    float2 p = (src ? targ : pred)[batch * NPTS + idx];
    int cx = min(max((int)(p.x * INV_CS), 0), GW - 1);
    int cy = min(max((int)(p.y * INV_CS), 0), GW - 1);
    int g = batch * 2 + src;
    int cell = g * NCELL + cy * GW + cx;
    u32 slot = atomicAdd(&cnt[cell], 1u);
    if (slot < CAP) {
        pts[(size_t)cell * CAP + slot] = p;
    } else {                                       // never in practice; exact fallback
        u32 o = atomicAdd(&ovfn[g], 1u);
        if (o < NOVF) ovf[(size_t)g * NOVF + o] = p;
    }
}

// One thread per (batch, dir, query point). Ring search over the target grid.
// Stop rule (exact): points in ring R' >= R lie at distance >= (R-1)*CS, so
// once best <= ((R-1)*CS)^2 before starting ring R, no farther ring can win.
__global__ __launch_bounds__(256) void hgrid_query(
    const float2* __restrict__ pred, const float2* __restrict__ targ,
    const u32* __restrict__ cnt, const float2* __restrict__ pts,
    const u32* __restrict__ ovfn, const float2* __restrict__ ovf,
    u32* __restrict__ hm)
{
    int bd = blockIdx.x >> 5, chunk = blockIdx.x & 31;   // 8 bd x 32 chunks
    int batch = bd >> 1, dir = bd & 1;
    int idx = chunk * 256 + threadIdx.x;
    float2 p = (dir ? targ : pred)[batch * NPTS + idx];  // query point
    int g = batch * 2 + (dir ^ 1);                       // target set's grid

    const u32*    ccnt = cnt + g * NCELL;
    const float2* cpts = pts + (size_t)g * NCELL * CAP;

    float best = 3.0e38f;

    // overflow candidates (normally zero; superset of real points is safe)
    u32 on = ovfn[g]; if (on > NOVF) on = NOVF;
    const float2* ov = ovf + (size_t)g * NOVF;
    for (u32 o = 0; o < on; ++o) {
        float2 q = ov[o];
        float dx = p.x - q.x, dy = p.y - q.y;
        best = fminf(best, fmaf(dx, dx, dy * dy));
    }

    int cx = min(max((int)(p.x * INV_CS), 0), GW - 1);
    int cy = min(max((int)(p.y * INV_CS), 0), GW - 1);

    auto scan = [&](int cxx, int cyy) {
        if (cxx < 0 || cxx >= GW || cyy < 0 || cyy >= GW) return;
        int c = cyy * GW + cxx;
        u32 n = ccnt[c]; if (n > CAP) n = CAP;
        const float2* cp = cpts + (size_t)c * CAP;
        for (u32 s = 0; s < n; ++s) {
            float2 q = cp[s];
            float dx = p.x - q.x, dy = p.y - q.y;
            best = fminf(best, fmaf(dx, dx, dy * dy));
        }
    };

    for (int R = 0; R < GW; ++R) {
        if (R >= 1) {
            float bound = (float)(R - 1) * CS;
            if (best <= bound * bound) break;
        }
        if (R == 0) {
            scan(cx, cy);
        } else {
            for (int dx = -R; dx <= R; ++dx) {
                scan(cx + dx, cy - R);
                scan(cx + dx, cy + R);
            }
            for (int dy = -R + 1; dy <= R - 1; ++dy) {
                scan(cx - R, cy + dy);
                scan(cx + R, cy + dy);
            }
        }
    }

    // best = exact min d2 for this query; fold MAX over the block (one bd/block)
    float v = best;
    #pragma unroll
    for (int o = 32; o; o >>= 1) v = fmaxf(v, __shfl_xor(v, o));
    __shared__ float sm[4];
    int wave = threadIdx.x >> 6, lane = threadIdx.x & 63;
    if (lane == 0) sm[wave] = v;
    __syncthreads();
    if (threadIdx.x == 0) {
        float bm = fmaxf(fmaxf(sm[0], sm[1]), fmaxf(sm[2], sm[3]));
        atomicMax(&hm[bd], __float_as_uint(bm));   // nonneg float bits: order-safe
    }
}

__global__ void hgrid_final(const u32* __restrict__ hm, float* __restrict__ out)
{
    if (threadIdx.x == 0 && blockIdx.x == 0) {
        float s = 0.0f;
        #pragma unroll
        for (int b = 0; b < NB; ++b) {
            float h0 = __uint_as_float(hm[2*b]);
            float h1 = __uint_as_float(hm[2*b + 1]);
            s += sqrtf(fmaxf(h0, h1));
        }
        out[0] = s * (1.0f / NB);
    }
}

extern "C" void kernel_launch(void* const* d_in, const int* in_sizes, int n_in,
                              void* d_out, int out_size, void* d_ws, size_t ws_size,
                              hipStream_t stream) {
    const float2* pred = (const float2*)d_in[0];   // [4,8192,2] f32
    const float2* targ = (const float2*)d_in[1];   // [4,8192,2] f32

    u32*    cnt  = (u32*)d_ws;
    u32*    ovfn = (u32*)((char*)d_ws + 131072);
    u32*    hm   = (u32*)((char*)d_ws + 131072 + 32);
    float2* pts  = (float2*)((char*)d_ws + (1u << 20));
    float2* ovf  = (float2*)((char*)d_ws + (6u << 20));

    // zero cnt + ovfn + hm
    hipMemsetAsync(d_ws, 0, 131072 + 64, stream);
    hipLaunchKernelGGL(hgrid_build, dim3(256), dim3(256), 0, stream,
                       pred, targ, cnt, pts, ovfn, ovf);
    hipLaunchKernelGGL(hgrid_query, dim3(256), dim3(256), 0, stream,
                       pred, targ, cnt, pts, ovfn, ovf, hm);
    hipLaunchKernelGGL(hgrid_final, dim3(1), dim3(64), 0, stream,
                       hm, (float*)d_out);
}

// Round 8
// 33.673 us; speedup vs baseline: 2.4134x; 1.2441x over previous
//
#include <hip/hip_runtime.h>
#include <math.h>

#define NPTS 8192
#define NB 4
#define GW 64                  // real grid is GW x GW cells
#define GP 66                  // padded grid (border of sentinel cells)
#define NCELLP (GP*GP)         // 4356
#define CS 8.0f                // cell size (512/GW)
#define INV_CS 0.125f
#define CAP 8                  // slots per cell (mean occupancy = 2)
#define NOVF 8192
#define SHIFT 1024.0f          // stored coord shift; sentinel 0 -> (-1024,-1024)

typedef unsigned int u32;

// ws layout (single zero memset covers cnt..pts):
//   [0, 139392)          cnt  u32[8][NCELLP]
//   [139392, +32)        ovfn u32[8]
//   [139424, +32)        hm   u32[8]     (max d2 bits, values >= 0)
//   [139520, +2230272)   pts  float2[8][NCELLP][CAP]   (stored +SHIFT; 0 = sentinel)
//   [4M, +512K)          ovf  float2[8][NOVF]          (raw coords, count-guarded)
#define OFF_OVFN 139392
#define OFF_HM   139424
#define OFF_PTS  139520
#define PTS_BYTES (8*NCELLP*CAP*8)          // 2230272
#define OFF_OVF  (4u<<20)

__global__ __launch_bounds__(256) void hgrid_build(
    const float2* __restrict__ pred, const float2* __restrict__ targ,
    u32* __restrict__ cnt, float2* __restrict__ pts,
    u32* __restrict__ ovfn, float2* __restrict__ ovf)
{
    int tid = blockIdx.x * 256 + threadIdx.x;      // 0..65535
    int src = tid >> 15, rem = tid & 32767;        // rem = batch*NPTS + idx
    float2 p = (src ? targ : pred)[rem];
    int batch = rem >> 13;
    int cx = min(max((int)(p.x * INV_CS), 0), GW - 1);
    int cy = min(max((int)(p.y * INV_CS), 0), GW - 1);
    int g = batch * 2 + src;
    int cell = g * NCELLP + (cy + 1) * GP + (cx + 1);
    u32 slot = atomicAdd(&cnt[cell], 1u);
    if (slot < CAP) {
        pts[(size_t)cell * CAP + slot] = make_float2(p.x + SHIFT, p.y + SHIFT);
    } else {                                       // rare exact fallback
        u32 o = atomicAdd(&ovfn[g], 1u);
        if (o < NOVF) ovf[(size_t)g * NOVF + o] = p;
    }
}

// 4 lanes per query. Unconditional sentinel-padded 3x3 scan, quad-min,
// exact ring fallback for the ~0.2% of queries with NN > CS.
__global__ __launch_bounds__(256) void hgrid_query(
    const float2* __restrict__ pred, const float2* __restrict__ targ,
    const float2* __restrict__ pts, const u32* __restrict__ ovfn,
    const float2* __restrict__ ovf, u32* __restrict__ hm)
{
    int blk = blockIdx.x;                          // 1024 = 8 bd x 128 chunks
    int bd = blk >> 7;
    int batch = bd >> 1, dir = bd & 1;
    int lq = threadIdx.x & 3;                      // lane within quad
    int q = (blk & 127) * 64 + (threadIdx.x >> 2); // query index
    float2 p = (dir ? targ : pred)[batch * NPTS + q];
    int g = batch * 2 + (dir ^ 1);                 // target set's grid

    const float4* gp4 = (const float4*)(pts + (size_t)g * NCELLP * CAP);
    float pxs = p.x + SHIFT, pys = p.y + SHIFT;
    int cx = min(max((int)(p.x * INV_CS), 0), GW - 1);
    int cy = min(max((int)(p.y * INV_CS), 0), GW - 1);
    int cbase = (cy + 1) * GP + (cx + 1);

    float best = 3.0e38f;
    auto scan_cell = [&](int c) {                  // 8 slots = 4 float4, no branches
        const float4* cp = gp4 + (size_t)c * 4;
        #pragma unroll
        for (int s = 0; s < 4; ++s) {
            float4 v = cp[s];
            float dx0 = pxs - v.x, dy0 = pys - v.y;
            float dx1 = pxs - v.z, dy1 = pys - v.w;
            best = fminf(best, fmaf(dx0, dx0, dy0 * dy0));
            best = fminf(best, fmaf(dx1, dx1, dy1 * dy1));
        }
    };

    // 3x3 neighborhood: cells t=0..8 split across the quad (border-padded: no checks)
    #pragma unroll
    for (int t = lq; t < 9; t += 4)
        scan_cell(cbase + (t / 3 - 1) * GP + (t % 3 - 1));

    // overflow candidates (normally ~0; superset scan is always safe)
    {
        u32 on = ovfn[g]; if (on > NOVF) on = NOVF;
        const float2* ov = ovf + (size_t)g * NOVF;
        for (u32 o = lq; o < on; o += 4) {
            float2 qv = ov[o];
            float dx = p.x - qv.x, dy = p.y - qv.y;
            best = fminf(best, fmaf(dx, dx, dy * dy));
        }
    }
    best = fminf(best, __shfl_xor(best, 1));
    best = fminf(best, __shfl_xor(best, 2));       // quad-uniform now

    // Exact ring search for hard queries. After rings <= R-1, unseen points
    // lie >= (R-1)*CS away -> stop when best <= ((R-1)*CS)^2.
    for (int R = 2; R < GW; ++R) {
        float bnd = (float)(R - 1) * CS;
        if (best <= bnd * bnd) break;
        int nc = 8 * R;
        for (int t = lq; t < nc; t += 4) {
            int cxx, cyy;
            if (t < 2 * R + 1)      { cxx = cx - R + t;               cyy = cy - R; }
            else if (t < 4 * R + 2) { cxx = cx - R + (t - (2*R + 1)); cyy = cy + R; }
            else { int s2 = t - (4*R + 2); cyy = cy - R + 1 + (s2 >> 1);
                   cxx = (s2 & 1) ? cx + R : cx - R; }
            if ((unsigned)cxx < GW && (unsigned)cyy < GW)
                scan_cell((cyy + 1) * GP + (cxx + 1));
        }
        best = fminf(best, __shfl_xor(best, 1));
        best = fminf(best, __shfl_xor(best, 2));
    }

    // block max-reduce (duplicates across quad lanes are harmless for max)
    float v = best;
    #pragma unroll
    for (int o = 32; o; o >>= 1) v = fmaxf(v, __shfl_xor(v, o));
    __shared__ float sm[4];
    int wave = threadIdx.x >> 6, lane = threadIdx.x & 63;
    if (lane == 0) sm[wave] = v;
    __syncthreads();
    if (threadIdx.x == 0) {
        float bm = fmaxf(fmaxf(sm[0], sm[1]), fmaxf(sm[2], sm[3]));
        atomicMax(&hm[bd], __float_as_uint(bm));
    }
}

__global__ void hgrid_final(const u32* __restrict__ hm, float* __restrict__ out)
{
    if (threadIdx.x == 0 && blockIdx.x == 0) {
        float s = 0.0f;
        #pragma unroll
        for (int b = 0; b < NB; ++b) {
            float h0 = __uint_as_float(hm[2*b]);
            float h1 = __uint_as_float(hm[2*b + 1]);
            s += sqrtf(fmaxf(h0, h1));
        }
        out[0] = s * (1.0f / NB);
    }
}

extern "C" void kernel_launch(void* const* d_in, const int* in_sizes, int n_in,
                              void* d_out, int out_size, void* d_ws, size_t ws_size,
                              hipStream_t stream) {
    const float2* pred = (const float2*)d_in[0];   // [4,8192,2] f32
    const float2* targ = (const float2*)d_in[1];   // [4,8192,2] f32

    u32*    cnt  = (u32*)d_ws;
    u32*    ovfn = (u32*)((char*)d_ws + OFF_OVFN);
    u32*    hm   = (u32*)((char*)d_ws + OFF_HM);
    float2* pts  = (float2*)((char*)d_ws + OFF_PTS);
    float2* ovf  = (float2*)((char*)d_ws + OFF_OVF);

    // one fill: zeroes cnt/ovfn/hm AND sentinel-fills pts (0 decodes to -1024)
    hipMemsetAsync(d_ws, 0, OFF_PTS + PTS_BYTES, stream);
    hipLaunchKernelGGL(hgrid_build, dim3(256), dim3(256), 0, stream,
                       pred, targ, cnt, pts, ovfn, ovf);
    hipLaunchKernelGGL(hgrid_query, dim3(1024), dim3(256), 0, stream,
                       pred, targ, pts, ovfn, ovf, hm);
    hipLaunchKernelGGL(hgrid_final, dim3(1), dim3(64), 0, stream,
                       hm, (float*)d_out);
}

// Round 9
// 20.434 us; speedup vs baseline: 3.9770x; 1.6479x over previous
//
#include <hip/hip_runtime.h>
#include <math.h>

#define NPTS   8192
#define NB     4
#define GW     34                   // grid GW x GW over [0,512)^2
#define NCELL  (GW*GW)              // 1156
#define CAP    12                   // slots/cell (48 B, 16B-aligned); lambda ~ 7.1
#define INV_CS (34.0f/512.0f)       // = 17/256, exact in f32
#define QS     96.0f                // coord quantization scale (512*96 = 49152 < 65535)
#define CSQ    (96.0f*512.0f/34.0f) // cell size in q-units (~1445.6)
#define INV_QS2 (1.0f/(96.0f*96.0f))
#define OVF_CAP 128                 // expected overflow ~40 pts/grid
#define NBLK   (NB*2*32)            // 256 blocks: 8 (batch,dir) x 32 query chunks

typedef unsigned int u32;

// One block = (batch, dir, 256 queries). Builds the WHOLE target-set grid in
// LDS (sentinel-padded, quantized u16x2), then answers its queries in-block.
// Cross-block state: one plain u32 store per block (slot[bid]); kernel
// boundary provides coherence for the reducer kernel. No memset, no fences.
__global__ __launch_bounds__(256) void haus_one(
    const float2* __restrict__ pred, const float2* __restrict__ targ,
    u32* __restrict__ slot)
{
    __shared__ u32 cells[NCELL*CAP];    // 55488 B, empty slots = 0xFFFFFFFF
    __shared__ u32 cnt[NCELL];          // 4624 B (build phase only)
    __shared__ u32 ovf[OVF_CAP];        // 512 B, CAP-overflow points
    __shared__ u32 ovfn;
    __shared__ float sred[4];

    int bid = blockIdx.x;
    int bd = bid >> 5, chunk = bid & 31;
    int batch = bd >> 1, dir = bd & 1;
    int tid = threadIdx.x;

    // ---- init LDS (sentinel decodes to (682.6, 682.6): >= 170 from any query)
    uint4* c4 = (uint4*)cells;
    for (int i = tid; i < NCELL*CAP/4; i += 256)
        c4[i] = make_uint4(~0u, ~0u, ~0u, ~0u);
    for (int i = tid; i < NCELL; i += 256) cnt[i] = 0;
    if (tid == 0) ovfn = 0;
    __syncthreads();

    // ---- build: bin the full target set (8192 pts) into the LDS grid
    const float4* tp = (const float4*)((dir ? pred : targ) + (size_t)batch*NPTS);
    #pragma unroll
    for (int k = 0; k < NPTS/512; ++k) {         // 16 x float4 = 32 pts/thread
        float4 v = tp[k*256 + tid];
        {
            int cx = min(max((int)(v.x*INV_CS),0),GW-1);
            int cy = min(max((int)(v.y*INV_CS),0),GW-1);
            u32 pk = (u32)(v.x*QS + 0.5f) | ((u32)(v.y*QS + 0.5f) << 16);
            int c = cy*GW + cx;
            u32 s = atomicAdd(&cnt[c], 1u);
            if (s < CAP) cells[c*CAP + s] = pk;
            else { u32 o = atomicAdd(&ovfn, 1u); if (o < OVF_CAP) ovf[o] = pk; }
        }
        {
            int cx = min(max((int)(v.z*INV_CS),0),GW-1);
            int cy = min(max((int)(v.w*INV_CS),0),GW-1);
            u32 pk = (u32)(v.z*QS + 0.5f) | ((u32)(v.w*QS + 0.5f) << 16);
            int c = cy*GW + cx;
            u32 s = atomicAdd(&cnt[c], 1u);
            if (s < CAP) cells[c*CAP + s] = pk;
            else { u32 o = atomicAdd(&ovfn, 1u); if (o < OVF_CAP) ovf[o] = pk; }
        }
    }
    __syncthreads();

    // ---- query: one exact-coord query per thread, all math in q-units
    int q = chunk*256 + tid;
    float2 p = ((dir ? targ : pred) + (size_t)batch*NPTS)[q];
    float qx = p.x * QS, qy = p.y * QS;
    int cx = min(max((int)(p.x*INV_CS),0),GW-1);
    int cy = min(max((int)(p.y*INV_CS),0),GW-1);

    float best = 3.0e38f;
    auto cand = [&](u32 w) {
        float ux = (float)(w & 0xFFFFu), uy = (float)(w >> 16);
        float dx = qx - ux, dy = qy - uy;
        best = fminf(best, fmaf(dx, dx, dy*dy));
    };
    auto scan = [&](int c) {                     // 12 slots = 3 x ds_read_b128
        const uint4* cp = (const uint4*)&cells[c*CAP];
        uint4 A = cp[0], B = cp[1], C = cp[2];
        cand(A.x); cand(A.y); cand(A.z); cand(A.w);
        cand(B.x); cand(B.y); cand(B.z); cand(B.w);
        cand(C.x); cand(C.y); cand(C.z); cand(C.w);
    };

    // clamped 3x3 (duplicate scans at borders are harmless for min)
    #pragma unroll
    for (int oy = -1; oy <= 1; ++oy) {
        int yy = min(max(cy+oy, 0), GW-1);
        #pragma unroll
        for (int ox = -1; ox <= 1; ++ox) {
            int xx = min(max(cx+ox, 0), GW-1);
            scan(yy*GW + xx);
        }
    }
    // CAP-overflow points: scanned by everyone (broadcast LDS reads)
    u32 on = ovfn; if (on > OVF_CAP) on = OVF_CAP;
    for (u32 o = 0; o < on; ++o) cand(ovf[o]);

    // exact ring fallback (P ~ e^-72: never taken; keeps result exact).
    // Unscanned cells at Chebyshev >= R hold points >= (R-1)*CS away;
    // -1 q-unit pads for stored-point quantization.
    for (int R = 2; R < GW; ++R) {
        float bnd = fmaf((float)(R-1), CSQ, -1.0f);
        if (best <= bnd*bnd) break;
        for (int t = 0; t < 8*R; ++t) {
            int cxx, cyy;
            if (t < 2*R+1)      { cxx = cx-R+t;          cyy = cy-R; }
            else if (t < 4*R+2) { cxx = cx-R+(t-2*R-1);  cyy = cy+R; }
            else { int s2 = t-4*R-2; cyy = cy-R+1+(s2>>1); cxx = (s2&1) ? cx+R : cx-R; }
            if ((unsigned)cxx < GW && (unsigned)cyy < GW) scan(cyy*GW + cxx);
        }
    }

    best *= INV_QS2;                             // back to real units (d^2)

    // block max-reduce -> one plain store
    float v = best;
    #pragma unroll
    for (int o = 32; o; o >>= 1) v = fmaxf(v, __shfl_xor(v, o));
    if ((tid & 63) == 0) sred[tid >> 6] = v;
    __syncthreads();
    if (tid == 0)
        slot[bid] = __float_as_uint(fmaxf(fmaxf(sred[0], sred[1]),
                                          fmaxf(sred[2], sred[3])));
}

// One wave: reduce 256 block-maxes (32 per (batch,dir)) -> final scalar.
__global__ __launch_bounds__(64) void haus_final(
    const u32* __restrict__ slot, float* __restrict__ out)
{
    int l = threadIdx.x;
    float m = 0.0f;
    #pragma unroll
    for (int k = 0; k < 4; ++k)                  // lane l: slots 4l..4l+3 (one bd)
        m = fmaxf(m, __uint_as_float(slot[l*4 + k]));
    m = fmaxf(m, __shfl_xor(m, 1));
    m = fmaxf(m, __shfl_xor(m, 2));
    m = fmaxf(m, __shfl_xor(m, 4));              // 8-lane group = one bd's 32 slots
    float s = 0.0f;
    #pragma unroll
    for (int b = 0; b < NB; ++b) {
        float h0 = __shfl(m, 16*b);              // bd = 2b   (lanes 16b..16b+7)
        float h1 = __shfl(m, 16*b + 8);          // bd = 2b+1
        s += sqrtf(fmaxf(h0, h1));
    }
    if (l == 0) out[0] = s * 0.25f;              // mean over batches
}

extern "C" void kernel_launch(void* const* d_in, const int* in_sizes, int n_in,
                              void* d_out, int out_size, void* d_ws, size_t ws_size,
                              hipStream_t stream) {
    const float2* pred = (const float2*)d_in[0];   // [4,8192,2] f32
    const float2* targ = (const float2*)d_in[1];   // [4,8192,2] f32
    u32* slot = (u32*)d_ws;                        // 256 u32; always fully written

    hipLaunchKernelGGL(haus_one, dim3(NBLK), dim3(256), 0, stream,
                       pred, targ, slot);
    hipLaunchKernelGGL(haus_final, dim3(1), dim3(64), 0, stream,
                       slot, (float*)d_out);
}